// Round 5
// baseline (1543.111 us; speedup 1.0000x reference)
//
#include <hip/hip_runtime.h>

// GCNConvSC: out = x + (D^-1/2 (A+I) D^-1/2) x W + b
// R5: kill k_fill (133us; 105MB partial-line writebacks for 6.4MB payload) and
// k_gather/k_cnt by coarse radix bucketing (dst>>7 -> 782 buckets of 128 nodes)
// + per-bucket LDS fp32 accumulation (64KB acc per block). All fine-grained
// scatter now lands in LDS; global writes are coalesced runs.
//
// Pipeline:
//  1. k_cvt    xh[r]=bf16(x[r]) into out rows' second 256B halves
//  2. k_hist   per-16384-edge-chunk histogram over NB buckets -> hist[k][blk]
//  3. k_part/k_mid/k_applyg   exclusive scan of hist (bucket-major) -> base
//  4. k_scat   re-read chunks, write (src,dst) pairs bucket-grouped (LDS fills)
//  5. k_dis    per-bucket degree count -> dis = rsqrt(cnt+1)
//  6. k_agg    block/bucket: LDS fp32 acc[128][128]; per edge: 256B bf16 row
//              load + 2 ds_add_f32/lane; epilogue adds self-loop, scales dd,
//              writes bf16 agg into out rows' first halves (coalesced)
//  7. k_gemm   out = x + agg @ W + b   (bf16 MFMA 16x16x32, W^T in LDS)

typedef __attribute__((ext_vector_type(8))) short short8;
typedef __attribute__((ext_vector_type(4))) float floatx4;

__device__ inline unsigned bf16rne(float f) {
    unsigned u = __builtin_bit_cast(unsigned, f);
    return (u + 0x7FFFu + ((u >> 16) & 1u)) >> 16;
}
__device__ inline unsigned pack2(float lo, float hi) {
    return bf16rne(lo) | (bf16rne(hi) << 16);
}
__device__ inline float bflo(unsigned u) { return __builtin_bit_cast(float, u << 16); }
__device__ inline float bfhi(unsigned u) { return __builtin_bit_cast(float, u & 0xFFFF0000u); }

#define CHUNK 16384   // edges per hist/scat block
#define NPB   128     // nodes per bucket (dst>>7)
#define MAXNB 1024    // LDS sizing bound for hist/fill arrays

__global__ void k_cvt(const float* __restrict__ x, char* __restrict__ outc, int N) {
    int t = blockIdx.x * blockDim.x + threadIdx.x;
    if (t >= N * 16) return;
    int r = t >> 4, g = t & 15;
    const float* p = x + (size_t)r * 128 + g * 8;
    float4 a = *(const float4*)p;
    float4 c = *(const float4*)(p + 4);
    uint4 v;
    v.x = pack2(a.x, a.y); v.y = pack2(a.z, a.w);
    v.z = pack2(c.x, c.y); v.w = pack2(c.z, c.w);
    *(uint4*)(outc + (size_t)r * 512 + 256 + g * 16) = v;
}

__global__ __launch_bounds__(256) void k_hist(const int* __restrict__ dst,
                                              int* __restrict__ hist,
                                              int E, int NB, int NBLK) {
    __shared__ int h[MAXNB];
    int tid = threadIdx.x, b = blockIdx.x;
    for (int i = tid; i < NB; i += 256) h[i] = 0;
    __syncthreads();
    int e0 = b * CHUNK, e1 = min(e0 + CHUNK, E);
    for (int e = e0 + tid; e < e1; e += 256) atomicAdd(&h[dst[e] >> 7], 1);
    __syncthreads();
    for (int k = tid; k < NB; k += 256) hist[(size_t)k * NBLK + b] = h[k];
}

// generic 3-kernel exclusive scan over M ints (M <= 128*1024)
__global__ __launch_bounds__(256) void k_part(const int* __restrict__ a,
                                              int* __restrict__ part, int M) {
    __shared__ int sums[256];
    int tid = threadIdx.x;
    int base = blockIdx.x * 1024 + tid * 4;
    int s = 0;
#pragma unroll
    for (int k = 0; k < 4; ++k) { int i = base + k; if (i < M) s += a[i]; }
    sums[tid] = s;
    __syncthreads();
    for (int off = 128; off > 0; off >>= 1) {
        if (tid < off) sums[tid] += sums[tid + off];
        __syncthreads();
    }
    if (tid == 0) part[blockIdx.x] = sums[0];
}

__global__ __launch_bounds__(128) void k_mid(int* __restrict__ part, int nblk) {
    __shared__ int s[128];
    int tid = threadIdx.x;
    s[tid] = (tid < nblk) ? part[tid] : 0;
    __syncthreads();
    for (int off = 1; off < 128; off <<= 1) {
        int v = (tid >= off) ? s[tid - off] : 0;
        __syncthreads();
        s[tid] += v;
        __syncthreads();
    }
    if (tid < nblk) part[tid] = tid ? s[tid - 1] : 0;
}

__global__ __launch_bounds__(256) void k_applyg(const int* __restrict__ a,
                                                const int* __restrict__ part,
                                                int* __restrict__ out, int M) {
    __shared__ int sums[256];
    int tid = threadIdx.x;
    int base = blockIdx.x * 1024 + tid * 4;
    int c[4];
    int s = 0;
#pragma unroll
    for (int k = 0; k < 4; ++k) {
        int i = base + k;
        c[k] = (i < M) ? a[i] : 0;
        s += c[k];
    }
    sums[tid] = s;
    __syncthreads();
    for (int off = 1; off < 256; off <<= 1) {
        int v = (tid >= off) ? sums[tid - off] : 0;
        __syncthreads();
        sums[tid] += v;
        __syncthreads();
    }
    int run = part[blockIdx.x] + (tid ? sums[tid - 1] : 0);
#pragma unroll
    for (int k = 0; k < 4; ++k) {
        int i = base + k;
        if (i < M) { out[i] = run; run += c[k]; }
    }
}

__global__ __launch_bounds__(256) void k_scat(const int* __restrict__ ei,
                                              const int* __restrict__ base,
                                              uint2* __restrict__ pairs,
                                              int E, int NB, int NBLK) {
    __shared__ int fill[MAXNB];
    int tid = threadIdx.x, b = blockIdx.x;
    for (int k = tid; k < NB; k += 256) fill[k] = base[(size_t)k * NBLK + b];
    __syncthreads();
    int e0 = b * CHUNK, e1 = min(e0 + CHUNK, E);
    for (int e = e0 + tid; e < e1; e += 256) {
        int s = ei[e];
        int d = ei[E + e];
        int pos = atomicAdd(&fill[d >> 7], 1);
        pairs[pos] = make_uint2((unsigned)s, (unsigned)d);
    }
}

__global__ __launch_bounds__(256) void k_dis(const uint2* __restrict__ pairs,
                                             const int* __restrict__ base,
                                             float* __restrict__ dis,
                                             int E, int NB, int NBLK, int N) {
    __shared__ int cnt[NPB];
    int tid = threadIdx.x, k = blockIdx.x;
    if (tid < NPB) cnt[tid] = 0;
    __syncthreads();
    int s0 = base[(size_t)k * NBLK];
    int s1 = (k + 1 < NB) ? base[(size_t)(k + 1) * NBLK] : E;
    for (int j = s0 + tid; j < s1; j += 256) atomicAdd(&cnt[pairs[j].y & (NPB - 1)], 1);
    __syncthreads();
    if (tid < NPB) {
        int gn = k * NPB + tid;
        if (gn < N) dis[gn] = rsqrtf((float)(cnt[tid] + 1));
    }
}

// one block per bucket; 512 thr = 8 waves; LDS fp32 acc[128 nodes][128 cols].
// wave processes groups of 4 edges (4 row loads in flight); lane covers 1 dword
// of the 256B bf16 row (2 cols) -> 2 ds_add_f32 per lane per edge.
__global__ __launch_bounds__(512) void k_agg(char* __restrict__ outc,
                                             const uint2* __restrict__ pairs,
                                             const int* __restrict__ base,
                                             const float* __restrict__ dis,
                                             int E, int NB, int NBLK, int N) {
    __shared__ float acc[NPB * 128];  // 64 KB
    int tid = threadIdx.x, k = blockIdx.x;
    for (int i = tid; i < NPB * 128; i += 512) acc[i] = 0.f;
    __syncthreads();

    int s0 = base[(size_t)k * NBLK];
    int s1 = (k + 1 < NB) ? base[(size_t)(k + 1) * NBLK] : E;
    int lane = tid & 63, wv = tid >> 6;

    for (int j = s0 + wv * 4; j < s1; j += 32) {
        uint2 p[4];
        float w[4];
        unsigned rv[4];
        int nval = min(4, s1 - j);
#pragma unroll
        for (int t = 0; t < 4; ++t) {
            if (t < nval) {
                p[t] = pairs[j + t];                       // wave-uniform (broadcast)
                w[t] = dis[p[t].x];
                rv[t] = *(const unsigned*)(outc + (size_t)p[t].x * 512 + 256 + lane * 4);
            }
        }
#pragma unroll
        for (int t = 0; t < 4; ++t) {
            if (t < nval) {
                int dloc = (int)(p[t].y & (NPB - 1));
                float* ap = acc + dloc * 128 + lane * 2;
                atomicAdd(ap,     w[t] * bflo(rv[t]));
                atomicAdd(ap + 1, w[t] * bfhi(rv[t]));
            }
        }
    }
    __syncthreads();

    // epilogue: 8 waves x 16 nodes each
    for (int n = wv; n < NPB; n += 8) {
        int gn = k * NPB + n;
        if (gn >= N) break;
        float dd = dis[gn];
        unsigned xh = *(const unsigned*)(outc + (size_t)gn * 512 + 256 + lane * 4);
        float v0 = dd * (acc[n * 128 + lane * 2]     + dd * bflo(xh));
        float v1 = dd * (acc[n * 128 + lane * 2 + 1] + dd * bfhi(xh));
        *(unsigned*)(outc + (size_t)gn * 512 + lane * 4) = pack2(v0, v1);
    }
}

// MFMA GEMM: block = 256 thr (4 waves), 128 rows/block (wave: 2 row-tiles of 16).
// A = agg_bf16 (out rows' first halves), B = W^T bf16 in LDS.
// C/D layout: col=lane&15, row=(lane>>4)*4+reg.
__global__ __launch_bounds__(256) void k_gemm(const float* __restrict__ x,
                                              const float* __restrict__ W,
                                              const float* __restrict__ bias,
                                              float* __restrict__ out, int N) {
    __shared__ short Wt[128 * 136];
    int tid = threadIdx.x;
    for (int i = tid; i < 8192; i += 256) {
        int n = i & 127, k2 = i >> 7;
        float w0 = W[(size_t)(2 * k2) * 128 + n];
        float w1 = W[(size_t)(2 * k2 + 1) * 128 + n];
        *(unsigned*)(Wt + (size_t)n * 136 + 2 * k2) = pack2(w0, w1);
    }
    __syncthreads();

    int lane = tid & 63, wv = tid >> 6;
    int quad = lane >> 4, l16 = lane & 15;
    size_t rowb = (size_t)blockIdx.x * 128 + wv * 32;
    const char* aggc = (const char*)out;

    floatx4 acc[2][8];
#pragma unroll
    for (int rt = 0; rt < 2; ++rt)
#pragma unroll
        for (int c = 0; c < 8; ++c) acc[rt][c] = (floatx4)0.0f;

    size_t r0 = rowb + l16;      if (r0 >= (size_t)N) r0 = N - 1;
    size_t r1 = rowb + 16 + l16; if (r1 >= (size_t)N) r1 = N - 1;

    for (int ks = 0; ks < 4; ++ks) {
        int koff = (quad * 8 + ks * 32) * 2;
        short8 a0 = *(const short8*)(aggc + r0 * 512 + koff);
        short8 a1 = *(const short8*)(aggc + r1 * 512 + koff);
#pragma unroll
        for (int c = 0; c < 8; ++c) {
            short8 bf = *(const short8*)(Wt + (size_t)(c * 16 + l16) * 136 + quad * 8 + ks * 32);
            acc[0][c] = __builtin_amdgcn_mfma_f32_16x16x32_bf16(a0, bf, acc[0][c], 0, 0, 0);
            acc[1][c] = __builtin_amdgcn_mfma_f32_16x16x32_bf16(a1, bf, acc[1][c], 0, 0, 0);
        }
    }

#pragma unroll
    for (int rt = 0; rt < 2; ++rt) {
#pragma unroll
        for (int c = 0; c < 8; ++c) {
            float bb = bias[c * 16 + l16];
#pragma unroll
            for (int r = 0; r < 4; ++r) {
                size_t row = rowb + rt * 16 + quad * 4 + r;
                if (row < (size_t)N) {
                    size_t idx = row * 128 + c * 16 + l16;
                    out[idx] = x[idx] + acc[rt][c][r] + bb;
                }
            }
        }
    }
}

extern "C" void kernel_launch(void* const* d_in, const int* in_sizes, int n_in,
                              void* d_out, int out_size, void* d_ws, size_t ws_size,
                              hipStream_t stream) {
    const float* x  = (const float*)d_in[0];
    const int*   ei = (const int*)d_in[1];   // [2, E]: src row then dst row
    const float* W  = (const float*)d_in[2];
    const float* b  = (const float*)d_in[3];
    float* out = (float*)d_out;

    int N = in_sizes[0] / 128;
    int E = in_sizes[1] / 2;
    int NB   = (N + NPB - 1) / NPB;          // 782 buckets
    int NBLK = (E + CHUNK - 1) / CHUNK;      // 98 chunks
    int M    = NB * NBLK;                    // 76636 (scan blocks = 75 <= 128)
    int nscan = (M + 1023) / 1024;

    // ws: pairs[E] uint2 | dis[N] | hist[M] | base[M] | part[128]
    char* w = (char*)d_ws;
    uint2* pairs = (uint2*)w;  w += (size_t)E * 8;
    float* dis   = (float*)w;  w += (size_t)N * 4;
    int*   hist  = (int*)w;    w += (size_t)M * 4;
    int*   base  = (int*)w;    w += (size_t)M * 4;
    int*   part  = (int*)w;

    k_cvt<<<(N * 16 + 255) / 256, 256, 0, stream>>>(x, (char*)out, N);
    k_hist<<<NBLK, 256, 0, stream>>>(ei + E, hist, E, NB, NBLK);
    k_part<<<nscan, 256, 0, stream>>>(hist, part, M);
    k_mid<<<1, 128, 0, stream>>>(part, nscan);
    k_applyg<<<nscan, 256, 0, stream>>>(hist, part, base, M);
    k_scat<<<NBLK, 256, 0, stream>>>(ei, base, pairs, E, NB, NBLK);
    k_dis<<<NB, 256, 0, stream>>>(pairs, base, dis, E, NB, NBLK, N);
    k_agg<<<NB, 512, 0, stream>>>((char*)out, pairs, base, dis, E, NB, NBLK, N);
    k_gemm<<<(N + 127) / 128, 256, 0, stream>>>(x, W, b, out, N);
}

// Round 6
// 293.242 us; speedup vs baseline: 5.2622x; 5.2622x over previous
//
#include <hip/hip_runtime.h>

// GCNConvSC: out = x + (D^-1/2 (A+I) D^-1/2) x W + b
// R6: R4 spine (395us) + bucket-sort CSR build replacing k_fill (133us of
// partial-line writebacks). LESSON (R5): fp32 atomicAdd on __shared__ takes
// the slow per-lane path (~150M/s, same as global); INT LDS atomics are fast
// (k_hist/k_scat evidence). So: no fp32 atomics anywhere.
//
// Pipeline:
//  1. k_cvt    xh[r]=bf16(x[r]) into out rows' second 256B halves
//  2. k_hist   per-16384-edge-chunk histogram over NB=782 buckets (dst>>7)
//  3. k_part/k_mid/k_applyg  exclusive scan of hist[k][blk] -> base; ptr[N]=E
//  4. k_scat   packed[pos] = src | (dst&127)<<17, bucket-grouped (int LDS fill)
//  5. k_sort   block/bucket: count+scan in LDS -> ptr, dis, dst-sorted csr_src
//  6. k_gather wave/node, quarter-wave/edge: agg[d]=dd*(sum dis_s*xh[s]+dd*xh[d])
//  7. k_gemm   out = x + agg @ W + b   (bf16 MFMA 16x16x32, W^T in LDS)

typedef __attribute__((ext_vector_type(8))) short short8;
typedef __attribute__((ext_vector_type(4))) float floatx4;

__device__ inline unsigned bf16rne(float f) {
    unsigned u = __builtin_bit_cast(unsigned, f);
    return (u + 0x7FFFu + ((u >> 16) & 1u)) >> 16;
}
__device__ inline unsigned pack2(float lo, float hi) {
    return bf16rne(lo) | (bf16rne(hi) << 16);
}
__device__ inline float bflo(unsigned u) { return __builtin_bit_cast(float, u << 16); }
__device__ inline float bfhi(unsigned u) { return __builtin_bit_cast(float, u & 0xFFFF0000u); }

#define CHUNK 16384   // edges per hist/scat block
#define NPB   128     // nodes per bucket (dst>>7)
#define MAXNB 1024    // LDS bound for hist/fill arrays (NB=782)
#define SRCB  17      // src bits in packed word (N=100000 < 2^17)
#define SRCMASK ((1u << SRCB) - 1u)

__global__ void k_cvt(const float* __restrict__ x, char* __restrict__ outc, int N) {
    int t = blockIdx.x * blockDim.x + threadIdx.x;
    if (t >= N * 16) return;
    int r = t >> 4, g = t & 15;
    const float* p = x + (size_t)r * 128 + g * 8;
    float4 a = *(const float4*)p;
    float4 c = *(const float4*)(p + 4);
    uint4 v;
    v.x = pack2(a.x, a.y); v.y = pack2(a.z, a.w);
    v.z = pack2(c.x, c.y); v.w = pack2(c.z, c.w);
    *(uint4*)(outc + (size_t)r * 512 + 256 + g * 16) = v;
}

__global__ __launch_bounds__(256) void k_hist(const int* __restrict__ dst,
                                              int* __restrict__ hist,
                                              int E, int NB, int NBLK) {
    __shared__ int h[MAXNB];
    int tid = threadIdx.x, b = blockIdx.x;
    for (int i = tid; i < NB; i += 256) h[i] = 0;
    __syncthreads();
    int e0 = b * CHUNK, e1 = min(e0 + CHUNK, E);
    for (int e = e0 + tid; e < e1; e += 256) atomicAdd(&h[dst[e] >> 7], 1);
    __syncthreads();
    for (int k = tid; k < NB; k += 256) hist[(size_t)k * NBLK + b] = h[k];
}

// 3-kernel exclusive scan over M ints (M <= 128*1024)
__global__ __launch_bounds__(256) void k_part(const int* __restrict__ a,
                                              int* __restrict__ part, int M) {
    __shared__ int sums[256];
    int tid = threadIdx.x;
    int base = blockIdx.x * 1024 + tid * 4;
    int s = 0;
#pragma unroll
    for (int k = 0; k < 4; ++k) { int i = base + k; if (i < M) s += a[i]; }
    sums[tid] = s;
    __syncthreads();
    for (int off = 128; off > 0; off >>= 1) {
        if (tid < off) sums[tid] += sums[tid + off];
        __syncthreads();
    }
    if (tid == 0) part[blockIdx.x] = sums[0];
}

__global__ __launch_bounds__(128) void k_mid(int* __restrict__ part,
                                             int* __restrict__ ptrN,
                                             int nblk, int E) {
    __shared__ int s[128];
    int tid = threadIdx.x;
    s[tid] = (tid < nblk) ? part[tid] : 0;
    __syncthreads();
    for (int off = 1; off < 128; off <<= 1) {
        int v = (tid >= off) ? s[tid - off] : 0;
        __syncthreads();
        s[tid] += v;
        __syncthreads();
    }
    if (tid < nblk) part[tid] = tid ? s[tid - 1] : 0;
    if (tid == 0) ptrN[0] = E;
}

__global__ __launch_bounds__(256) void k_applyg(const int* __restrict__ a,
                                                const int* __restrict__ part,
                                                int* __restrict__ out, int M) {
    __shared__ int sums[256];
    int tid = threadIdx.x;
    int base = blockIdx.x * 1024 + tid * 4;
    int c[4];
    int s = 0;
#pragma unroll
    for (int k = 0; k < 4; ++k) {
        int i = base + k;
        c[k] = (i < M) ? a[i] : 0;
        s += c[k];
    }
    sums[tid] = s;
    __syncthreads();
    for (int off = 1; off < 256; off <<= 1) {
        int v = (tid >= off) ? sums[tid - off] : 0;
        __syncthreads();
        sums[tid] += v;
        __syncthreads();
    }
    int run = part[blockIdx.x] + (tid ? sums[tid - 1] : 0);
#pragma unroll
    for (int k = 0; k < 4; ++k) {
        int i = base + k;
        if (i < M) { out[i] = run; run += c[k]; }
    }
}

__global__ __launch_bounds__(256) void k_scat(const int* __restrict__ ei,
                                              const int* __restrict__ base,
                                              unsigned* __restrict__ packed,
                                              int E, int NB, int NBLK) {
    __shared__ int fill[MAXNB];
    int tid = threadIdx.x, b = blockIdx.x;
    for (int k = tid; k < NB; k += 256) fill[k] = base[(size_t)k * NBLK + b];
    __syncthreads();
    int e0 = b * CHUNK, e1 = min(e0 + CHUNK, E);
    for (int e = e0 + tid; e < e1; e += 256) {
        int s = ei[e];
        int d = ei[E + e];
        int pos = atomicAdd(&fill[d >> 7], 1);
        packed[pos] = (unsigned)s | ((unsigned)(d & (NPB - 1)) << SRCB);
    }
}

// one block per bucket: counting-sort its segment by local dst.
// All global writes land in this block's own ~8KB segment (L2-combined).
__global__ __launch_bounds__(256) void k_sort(const unsigned* __restrict__ packed,
                                              const int* __restrict__ base,
                                              int* __restrict__ csr_src,
                                              int* __restrict__ ptr,
                                              float* __restrict__ dis,
                                              int E, int NB, int NBLK, int N) {
    __shared__ int cnt[NPB], scn[NPB], fill[NPB];
    int tid = threadIdx.x, k = blockIdx.x;
    int s0 = base[(size_t)k * NBLK];
    int s1 = (k + 1 < NB) ? base[(size_t)(k + 1) * NBLK] : E;
    if (tid < NPB) cnt[tid] = 0;
    __syncthreads();
    for (int j = s0 + tid; j < s1; j += 256) atomicAdd(&cnt[packed[j] >> SRCB], 1);
    __syncthreads();
    if (tid < NPB) scn[tid] = cnt[tid];
    __syncthreads();
    for (int off = 1; off < NPB; off <<= 1) {
        int v = (tid < NPB && tid >= off) ? scn[tid - off] : 0;
        __syncthreads();
        if (tid < NPB) scn[tid] += v;
        __syncthreads();
    }
    if (tid < NPB) {
        int excl = scn[tid] - cnt[tid];
        fill[tid] = excl;
        int gn = k * NPB + tid;
        if (gn < N) {
            ptr[gn] = s0 + excl;
            dis[gn] = rsqrtf((float)(cnt[tid] + 1));  // +1 self loop
        }
    }
    __syncthreads();
    for (int j = s0 + tid; j < s1; j += 256) {
        unsigned p = packed[j];
        int loc = atomicAdd(&fill[p >> SRCB], 1);
        csr_src[s0 + loc] = (int)(p & SRCMASK);
    }
}

// one wave per node; quarter-wave q (16 lanes x 16B = 256B bf16 row) handles
// edges j = lo+q, lo+q+4, ...  4 rows in flight per wave.
__global__ __launch_bounds__(256) void k_gather(char* __restrict__ outc,
                                                const int* __restrict__ csr_src,
                                                const int* __restrict__ ptr,
                                                const float* __restrict__ dis,
                                                int N) {
    int lane = threadIdx.x & 63;
    int q = lane >> 4, sub = lane & 15;
    int node = (blockIdx.x * blockDim.x + threadIdx.x) >> 6;
    if (node >= N) return;
    int lo = ptr[node], hi = ptr[node + 1];
    float dd = dis[node];

    float acc[8] = {0.f, 0.f, 0.f, 0.f, 0.f, 0.f, 0.f, 0.f};
    for (int j = lo + q; j < hi; j += 4) {
        int s = csr_src[j];
        float w = dis[s];
        uint4 v = *(const uint4*)(outc + (size_t)s * 512 + 256 + sub * 16);
        acc[0] = fmaf(w, bflo(v.x), acc[0]);
        acc[1] = fmaf(w, bfhi(v.x), acc[1]);
        acc[2] = fmaf(w, bflo(v.y), acc[2]);
        acc[3] = fmaf(w, bfhi(v.y), acc[3]);
        acc[4] = fmaf(w, bflo(v.z), acc[4]);
        acc[5] = fmaf(w, bfhi(v.z), acc[5]);
        acc[6] = fmaf(w, bflo(v.w), acc[6]);
        acc[7] = fmaf(w, bfhi(v.w), acc[7]);
    }
    if (q == 0) {  // self-loop term, once
        uint4 v = *(const uint4*)(outc + (size_t)node * 512 + 256 + sub * 16);
        acc[0] = fmaf(dd, bflo(v.x), acc[0]);
        acc[1] = fmaf(dd, bfhi(v.x), acc[1]);
        acc[2] = fmaf(dd, bflo(v.y), acc[2]);
        acc[3] = fmaf(dd, bfhi(v.y), acc[3]);
        acc[4] = fmaf(dd, bflo(v.z), acc[4]);
        acc[5] = fmaf(dd, bfhi(v.z), acc[5]);
        acc[6] = fmaf(dd, bflo(v.w), acc[6]);
        acc[7] = fmaf(dd, bfhi(v.w), acc[7]);
    }
#pragma unroll
    for (int i = 0; i < 8; ++i) {
        acc[i] += __shfl_xor(acc[i], 16);
        acc[i] += __shfl_xor(acc[i], 32);
    }
    if (q == 0) {
        uint4 o;
        o.x = pack2(dd * acc[0], dd * acc[1]);
        o.y = pack2(dd * acc[2], dd * acc[3]);
        o.z = pack2(dd * acc[4], dd * acc[5]);
        o.w = pack2(dd * acc[6], dd * acc[7]);
        *(uint4*)(outc + (size_t)node * 512 + sub * 16) = o;
    }
}

// MFMA GEMM: block = 256 thr (4 waves), 128 rows/block (wave: 2 row-tiles of 16).
// A = agg_bf16 (out rows' first halves), B = W^T bf16 in LDS.
// C/D layout: col=lane&15, row=(lane>>4)*4+reg.
__global__ __launch_bounds__(256) void k_gemm(const float* __restrict__ x,
                                              const float* __restrict__ W,
                                              const float* __restrict__ bias,
                                              float* __restrict__ out, int N) {
    __shared__ short Wt[128 * 136];
    int tid = threadIdx.x;
    for (int i = tid; i < 8192; i += 256) {
        int n = i & 127, k2 = i >> 7;
        float w0 = W[(size_t)(2 * k2) * 128 + n];
        float w1 = W[(size_t)(2 * k2 + 1) * 128 + n];
        *(unsigned*)(Wt + (size_t)n * 136 + 2 * k2) = pack2(w0, w1);
    }
    __syncthreads();

    int lane = tid & 63, wv = tid >> 6;
    int quad = lane >> 4, l16 = lane & 15;
    size_t rowb = (size_t)blockIdx.x * 128 + wv * 32;
    const char* aggc = (const char*)out;

    floatx4 acc[2][8];
#pragma unroll
    for (int rt = 0; rt < 2; ++rt)
#pragma unroll
        for (int c = 0; c < 8; ++c) acc[rt][c] = (floatx4)0.0f;

    size_t r0 = rowb + l16;      if (r0 >= (size_t)N) r0 = N - 1;
    size_t r1 = rowb + 16 + l16; if (r1 >= (size_t)N) r1 = N - 1;

    for (int ks = 0; ks < 4; ++ks) {
        int koff = (quad * 8 + ks * 32) * 2;
        short8 a0 = *(const short8*)(aggc + r0 * 512 + koff);
        short8 a1 = *(const short8*)(aggc + r1 * 512 + koff);
#pragma unroll
        for (int c = 0; c < 8; ++c) {
            short8 bf = *(const short8*)(Wt + (size_t)(c * 16 + l16) * 136 + quad * 8 + ks * 32);
            acc[0][c] = __builtin_amdgcn_mfma_f32_16x16x32_bf16(a0, bf, acc[0][c], 0, 0, 0);
            acc[1][c] = __builtin_amdgcn_mfma_f32_16x16x32_bf16(a1, bf, acc[1][c], 0, 0, 0);
        }
    }

#pragma unroll
    for (int rt = 0; rt < 2; ++rt) {
#pragma unroll
        for (int c = 0; c < 8; ++c) {
            float bb = bias[c * 16 + l16];
#pragma unroll
            for (int r = 0; r < 4; ++r) {
                size_t row = rowb + rt * 16 + quad * 4 + r;
                if (row < (size_t)N) {
                    size_t idx = row * 128 + c * 16 + l16;
                    out[idx] = x[idx] + acc[rt][c][r] + bb;
                }
            }
        }
    }
}

extern "C" void kernel_launch(void* const* d_in, const int* in_sizes, int n_in,
                              void* d_out, int out_size, void* d_ws, size_t ws_size,
                              hipStream_t stream) {
    const float* x  = (const float*)d_in[0];
    const int*   ei = (const int*)d_in[1];   // [2, E]: src row then dst row
    const float* W  = (const float*)d_in[2];
    const float* b  = (const float*)d_in[3];
    float* out = (float*)d_out;

    int N = in_sizes[0] / 128;
    int E = in_sizes[1] / 2;
    int NB   = (N + NPB - 1) / NPB;          // 782 buckets
    int NBLK = (E + CHUNK - 1) / CHUNK;      // 98 chunks
    int M    = NB * NBLK;                    // 76636
    int nscan = (M + 1023) / 1024;           // 75 (<=128)

    // ws: packed[E] | csr_src[E] | dis[N] | ptr[N+1] | hist[M] | base[M] | part[128]
    char* w = (char*)d_ws;
    unsigned* packed = (unsigned*)w; w += (size_t)E * 4;
    int*   csr_src = (int*)w;   w += (size_t)E * 4;
    float* dis     = (float*)w; w += (size_t)N * 4;
    int*   ptr     = (int*)w;   w += (size_t)(N + 1) * 4;
    int*   hist    = (int*)w;   w += (size_t)M * 4;
    int*   base    = (int*)w;   w += (size_t)M * 4;
    int*   part    = (int*)w;

    k_cvt<<<(N * 16 + 255) / 256, 256, 0, stream>>>(x, (char*)out, N);
    k_hist<<<NBLK, 256, 0, stream>>>(ei + E, hist, E, NB, NBLK);
    k_part<<<nscan, 256, 0, stream>>>(hist, part, M);
    k_mid<<<1, 128, 0, stream>>>(part, ptr + N, nscan, E);
    k_applyg<<<nscan, 256, 0, stream>>>(hist, part, base, M);
    k_scat<<<NBLK, 256, 0, stream>>>(ei, base, packed, E, NB, NBLK);
    k_sort<<<NB, 256, 0, stream>>>(packed, base, csr_src, ptr, dis, E, NB, NBLK, N);
    k_gather<<<((size_t)N * 64 + 255) / 256, 256, 0, stream>>>((char*)out, csr_src, ptr, dis, N);
    k_gemm<<<(N + 127) / 128, 256, 0, stream>>>(x, W, b, out, N);
}